// Round 11
// baseline (156.388 us; speedup 1.0000x reference)
//
#include <hip/hip_runtime.h>

#define Lr 2048
#define Dr 1024
#define Nr 16
#define Gc 64           // chunks along L
#define LC (Lr/Gc)      // 32
#define DN (Dr*Nr)      // 16384
#define GDN (Gc*DN)

#define LOG2E 1.442695041f
#define LN2   0.69314718056f

typedef float f32x4 __attribute__((ext_vector_type(4)));

__device__ __forceinline__ float exp2_hw(float x){ return __builtin_amdgcn_exp2f(x); }
__device__ __forceinline__ float log2_hw(float x){ return __builtin_amdgcn_logf(x); }
__device__ __forceinline__ float exp_hw(float x) { return exp2_hw(x*LOG2E); }
__device__ __forceinline__ float softplus_fast(float x){
  float t = exp2_hw(-LOG2E*fabsf(x));
  return fmaxf(x, 0.f) + LN2*log2_hw(1.f + t);
}

// z[l] = dot(xs[l,:], WD) + bD  (8 KB output; separate kernel is right —
// folding into phase kernels costs 16x redundant xs reads, +50us measured R9)
__global__ void k_rowdot(const float* __restrict__ xs, const float* __restrict__ WD,
                         const float* __restrict__ bD, float* __restrict__ z){
  int l = blockIdx.x;
  const float4* row = (const float4*)(xs + (size_t)l*Dr);
  const float4* w4  = (const float4*)WD;
  int i = threadIdx.x;           // Dr/4 == 256 == blockDim
  float4 a = row[i], b = w4[i];
  float s = fmaf(a.x,b.x, fmaf(a.y,b.y, fmaf(a.z,b.z, a.w*b.w)));
  #pragma unroll
  for (int off = 32; off > 0; off >>= 1) s += __shfl_down(s, off, 64);
  __shared__ float red[4];
  int wid = threadIdx.x >> 6, lane = threadIdx.x & 63;
  if (lane == 0) red[wid] = s;
  __syncthreads();
  if (threadIdx.x == 0) z[l] = red[0] + red[1] + red[2] + red[3] + bD[0];
}

// Phase 1 (proven R5 form): thread per (g, d, n-quad); 4 chains/thread.
__global__ __launch_bounds__(256) void k_phase1(
    const float* __restrict__ xs, const float* __restrict__ WB,
    const float* __restrict__ bB,
    const float* __restrict__ lnA, const float* __restrict__ dparam,
    const float* __restrict__ z,
    float* __restrict__ aggA, float* __restrict__ aggB){
  int t  = blockIdx.x*256 + threadIdx.x;
  int g  = t >> 12;             // Dr*4 = 4096 threads per chunk
  int r  = t & 4095;
  int d  = r >> 2;
  int n4 = r & 3;
  float4 la = *(const float4*)(lnA + d*Nr + n4*4);
  float4 wb = *(const float4*)(WB  + n4*4);
  float4 bb = *(const float4*)(bB  + n4*4);
  float lav[4] = {la.x,la.y,la.z,la.w};
  float wbv[4] = {wb.x,wb.y,wb.z,wb.w};
  float bbv[4] = {bb.x,bb.y,bb.z,bb.w};
  float ad2[4], p[4], q[4], Ap[4], Bc[4];
  #pragma unroll
  for (int j=0;j<4;j++){
    float a = -exp_hw(lav[j]);
    ad2[j] = a*LOG2E;
    float ia = 1.f/a;
    p[j]=wbv[j]*ia; q[j]=bbv[j]*ia; Ap[j]=1.f; Bc[j]=0.f;
  }
  float dp = dparam[d];
  int l0 = g*LC;
  #pragma unroll 2
  for (int i=0;i<LC;i++){
    int l = l0+i;
    float x  = xs[(size_t)l*Dr + d];
    float dl = softplus_fast(dp + z[l]);
    float x2 = x*x;
    #pragma unroll
    for (int j=0;j<4;j++){
      float Ab = exp2_hw(dl*ad2[j]);
      float Bx = (Ab-1.f)*fmaf(x2, p[j], x*q[j]);
      Ap[j] *= Ab;
      Bc[j] = fmaf(Ab, Bc[j], Bx);
    }
  }
  *(float4*)(aggA + (size_t)g*DN + d*Nr + n4*4) = make_float4(Ap[0],Ap[1],Ap[2],Ap[3]);
  *(float4*)(aggB + (size_t)g*DN + d*Nr + n4*4) = make_float4(Bc[0],Bc[1],Bc[2],Bc[3]);
}

// Phase 2: per-chain serial scan over 64 chunks; unroll 16 (4 load batches).
__global__ __launch_bounds__(64) void k_carry(
    const float* __restrict__ aggA, const float* __restrict__ aggB,
    float* __restrict__ carry){
  const int t = blockIdx.x*64 + threadIdx.x;   // chain id = d*Nr+n
  float h = 0.f;
  for (int g0 = 0; g0 < Gc; g0 += 16){
    float A_[16], B_[16];
    #pragma unroll
    for (int k=0;k<16;k++){
      A_[k] = aggA[(size_t)(g0+k)*DN + t];
      B_[k] = aggB[(size_t)(g0+k)*DN + t];
    }
    #pragma unroll
    for (int k=0;k<16;k++){
      carry[(size_t)(g0+k)*DN + t] = h;
      h = fmaf(A_[k], h, B_[k]);
    }
  }
}

// Phase 3: 16 chains/thread — thread owns (g,d), ALL n. 64B/lane contiguous
// nontemporal hs stores (wave = 4KB); ys fully in-register (no shuffle,
// no divergent store). Grid = Gc*Dr/256 = 256 blocks; fills prove ~1 wave/SIMD
// saturates write BW, so low block count is fine here.
__global__ __launch_bounds__(256) void k_phase3(
    const float* __restrict__ xs, const float* __restrict__ WB,
    const float* __restrict__ bB, const float* __restrict__ WC,
    const float* __restrict__ bC,
    const float* __restrict__ lnA, const float* __restrict__ dparam,
    const float* __restrict__ z, const float* __restrict__ carry,
    float* __restrict__ ys, float* __restrict__ hs){
  int tid = blockIdx.x*256 + threadIdx.x;
  int d   = tid & (Dr-1);
  int g   = tid >> 10;
  float ad2[16], p[16], q[16], wc[16], bc[16], h[16];
  {
    const f32x4* lap = (const f32x4*)(lnA + d*Nr);
    const f32x4* cp  = (const f32x4*)(carry + (size_t)g*DN + d*Nr);
    const f32x4* wbp = (const f32x4*)WB;
    const f32x4* bbp = (const f32x4*)bB;
    const f32x4* wcp = (const f32x4*)WC;
    const f32x4* bcp = (const f32x4*)bC;
    #pragma unroll
    for (int v=0; v<4; v++){
      f32x4 lav = lap[v], hv = cp[v], wbv = wbp[v], bbv = bbp[v];
      f32x4 wcv = wcp[v], bcv = bcp[v];
      #pragma unroll
      for (int e=0; e<4; e++){
        int j = v*4+e;
        float a = -exp_hw(lav[e]);
        ad2[j] = a*LOG2E;
        float ia = 1.f/a;
        p[j] = wbv[e]*ia; q[j] = bbv[e]*ia;
        wc[j] = wcv[e]; bc[j] = bcv[e];
        h[j] = hv[e];
      }
    }
  }
  const float dp = dparam[d];
  const int l0 = g*LC;
  for (int i=0;i<LC;i++){
    int l = l0+i;
    float x  = xs[(size_t)l*Dr + d];
    float dl = softplus_fast(dp + z[l]);
    float x2 = x*x;
    float y = 0.f;
    #pragma unroll
    for (int j=0;j<16;j++){
      float Ab = exp2_hw(dl*ad2[j]);
      float Bx = (Ab-1.f)*fmaf(x2, p[j], x*q[j]);
      h[j] = fmaf(Ab, h[j], Bx);
      y = fmaf(h[j], fmaf(x, wc[j], bc[j]), y);
    }
    float* hp = hs + (size_t)l*DN + d*Nr;
    #pragma unroll
    for (int v=0; v<4; v++){
      f32x4 hv = {h[v*4+0],h[v*4+1],h[v*4+2],h[v*4+3]};
      __builtin_nontemporal_store(hv, (f32x4*)(hp + v*4));
    }
    __builtin_nontemporal_store(y, ys + (size_t)l*Dr + d);
  }
}

extern "C" void kernel_launch(void* const* d_in, const int* in_sizes, int n_in,
                              void* d_out, int out_size, void* d_ws, size_t ws_size,
                              hipStream_t stream) {
  const float* xs     = (const float*)d_in[0];
  const float* WB     = (const float*)d_in[1];
  const float* bB     = (const float*)d_in[2];
  const float* WC     = (const float*)d_in[3];
  const float* bC     = (const float*)d_in[4];
  const float* WD     = (const float*)d_in[5];
  const float* bD     = (const float*)d_in[6];
  const float* lnA    = (const float*)d_in[7];
  const float* dparam = (const float*)d_in[8];

  float* ys = (float*)d_out;
  float* hs = ys + (size_t)Lr*Dr;

  float* z     = (float*)d_ws;          // Lr
  float* aggA  = z + Lr;                // GDN
  float* aggB  = aggA + GDN;            // GDN
  float* carry = aggB + GDN;            // GDN  (total ~12.6 MB)

  k_rowdot<<<Lr, 256, 0, stream>>>(xs, WD, bD, z);
  k_phase1<<<(Gc*Dr*4)/256, 256, 0, stream>>>(xs, WB, bB, lnA, dparam, z, aggA, aggB);
  k_carry<<<DN/64, 64, 0, stream>>>(aggA, aggB, carry);
  k_phase3<<<(Gc*Dr)/256, 256, 0, stream>>>(xs, WB, bB, WC, bC, lnA, dparam, z, carry, ys, hs);
}

// Round 12
// 67.753 us; speedup vs baseline: 2.3082x; 2.3082x over previous
//
#include <hip/hip_runtime.h>

#define Lr 2048
#define Dr 1024
#define Nr 16
#define Gc 64           // chunks along L
#define LC (Lr/Gc)      // 32
#define DN (Dr*Nr)      // 16384
#define GDN (Gc*DN)

#define LOG2E 1.442695041f
#define LN2   0.69314718056f

typedef float f32x4 __attribute__((ext_vector_type(4)));

__device__ __forceinline__ float exp2_hw(float x){ return __builtin_amdgcn_exp2f(x); }
__device__ __forceinline__ float log2_hw(float x){ return __builtin_amdgcn_logf(x); }
__device__ __forceinline__ float exp_hw(float x) { return exp2_hw(x*LOG2E); }
__device__ __forceinline__ float softplus_fast(float x){
  float t = exp2_hw(-LOG2E*fabsf(x));
  return fmaxf(x, 0.f) + LN2*log2_hw(1.f + t);
}

// z[l] = dot(xs[l,:], WD) + bD  (separate tiny kernel is right: folding it
// into phase kernels costs 16x redundant xs reads, +50us measured in R9)
__global__ void k_rowdot(const float* __restrict__ xs, const float* __restrict__ WD,
                         const float* __restrict__ bD, float* __restrict__ z){
  int l = blockIdx.x;
  const float4* row = (const float4*)(xs + (size_t)l*Dr);
  const float4* w4  = (const float4*)WD;
  int i = threadIdx.x;           // Dr/4 == 256 == blockDim
  float4 a = row[i], b = w4[i];
  float s = fmaf(a.x,b.x, fmaf(a.y,b.y, fmaf(a.z,b.z, a.w*b.w)));
  #pragma unroll
  for (int off = 32; off > 0; off >>= 1) s += __shfl_down(s, off, 64);
  __shared__ float red[4];
  int wid = threadIdx.x >> 6, lane = threadIdx.x & 63;
  if (lane == 0) red[wid] = s;
  __syncthreads();
  if (threadIdx.x == 0) z[l] = red[0] + red[1] + red[2] + red[3] + bD[0];
}

// Phase 1: d-FASTEST lane map (lane = consecutive d -> 256B coalesced xs
// loads). agg stores are 64B-strided float4 but PLAIN (L2-merged; agg is
// L2-resident for k_carry). 4 chains/thread (one n-quad).
__global__ __launch_bounds__(256) void k_phase1(
    const float* __restrict__ xs, const float* __restrict__ WB,
    const float* __restrict__ bB,
    const float* __restrict__ lnA, const float* __restrict__ dparam,
    const float* __restrict__ z,
    float* __restrict__ aggA, float* __restrict__ aggB){
  int t  = blockIdx.x*256 + threadIdx.x;
  int g  = t >> 12;             // 4096 threads per chunk
  int r  = t & 4095;
  int n4 = r >> 10;             // 0..3  (slow)
  int d  = r & (Dr-1);          // fast: consecutive lanes = consecutive d
  float4 la = *(const float4*)(lnA + d*Nr + n4*4);
  float4 wb = *(const float4*)(WB  + n4*4);
  float4 bb = *(const float4*)(bB  + n4*4);
  float lav[4] = {la.x,la.y,la.z,la.w};
  float wbv[4] = {wb.x,wb.y,wb.z,wb.w};
  float bbv[4] = {bb.x,bb.y,bb.z,bb.w};
  float ad2[4], p[4], q[4], Ap[4], Bc[4];
  #pragma unroll
  for (int j=0;j<4;j++){
    float a = -exp_hw(lav[j]);
    ad2[j] = a*LOG2E;
    float ia = 1.f/a;
    p[j]=wbv[j]*ia; q[j]=bbv[j]*ia; Ap[j]=1.f; Bc[j]=0.f;
  }
  float dp = dparam[d];
  int l0 = g*LC;
  #pragma unroll 2
  for (int i=0;i<LC;i++){
    int l = l0+i;
    float x  = xs[(size_t)l*Dr + d];
    float dl = softplus_fast(dp + z[l]);
    float x2 = x*x;
    #pragma unroll
    for (int j=0;j<4;j++){
      float Ab = exp2_hw(dl*ad2[j]);
      float Bx = (Ab-1.f)*fmaf(x2, p[j], x*q[j]);
      Ap[j] *= Ab;
      Bc[j] = fmaf(Ab, Bc[j], Bx);
    }
  }
  *(float4*)(aggA + (size_t)g*DN + d*Nr + n4*4) = make_float4(Ap[0],Ap[1],Ap[2],Ap[3]);
  *(float4*)(aggB + (size_t)g*DN + d*Nr + n4*4) = make_float4(Bc[0],Bc[1],Bc[2],Bc[3]);
}

// Phase 2: per-chain serial scan over 64 chunks; unroll 16 (32 loads in flight).
__global__ __launch_bounds__(64) void k_carry(
    const float* __restrict__ aggA, const float* __restrict__ aggB,
    float* __restrict__ carry){
  const int t = blockIdx.x*64 + threadIdx.x;   // chain id = d*Nr+n
  float h = 0.f;
  for (int g0 = 0; g0 < Gc; g0 += 16){
    float A_[16], B_[16];
    #pragma unroll
    for (int k=0;k<16;k++){
      A_[k] = aggA[(size_t)(g0+k)*DN + t];
      B_[k] = aggB[(size_t)(g0+k)*DN + t];
    }
    #pragma unroll
    for (int k=0;k<16;k++){
      carry[(size_t)(g0+k)*DN + t] = h;
      h = fmaf(A_[k], h, B_[k]);
    }
  }
}

// Phase 3 (R5-proven form): n4-FASTEST lane map -> each f32x4 nontemporal
// store is wave-contiguous 1KB (full cache lines; nt needs this — 64B-stride
// nt stores showed 2x write amplification in R11). 4 chains/thread.
__global__ __launch_bounds__(256) void k_phase3(
    const float* __restrict__ xs, const float* __restrict__ WB,
    const float* __restrict__ bB, const float* __restrict__ WC,
    const float* __restrict__ bC,
    const float* __restrict__ lnA, const float* __restrict__ dparam,
    const float* __restrict__ z, const float* __restrict__ carry,
    float* __restrict__ ys, float* __restrict__ hs){
  int t  = blockIdx.x*256 + threadIdx.x;
  int g  = t >> 12;
  int r  = t & 4095;
  int d  = r >> 2;
  int n4 = r & 3;
  float4 la = *(const float4*)(lnA + d*Nr + n4*4);
  float4 wb = *(const float4*)(WB  + n4*4);
  float4 bb = *(const float4*)(bB  + n4*4);
  float4 wcv= *(const float4*)(WC  + n4*4);
  float4 bcv= *(const float4*)(bC  + n4*4);
  float4 h0 = *(const float4*)(carry + (size_t)g*DN + d*Nr + n4*4);
  float lav[4] = {la.x,la.y,la.z,la.w};
  float wbv[4] = {wb.x,wb.y,wb.z,wb.w};
  float bbv[4] = {bb.x,bb.y,bb.z,bb.w};
  float wc[4]  = {wcv.x,wcv.y,wcv.z,wcv.w};
  float bc[4]  = {bcv.x,bcv.y,bcv.z,bcv.w};
  float h[4]   = {h0.x,h0.y,h0.z,h0.w};
  float ad2[4], p[4], q[4];
  #pragma unroll
  for (int j=0;j<4;j++){
    float a = -exp_hw(lav[j]);
    ad2[j] = a*LOG2E;
    float ia = 1.f/a;
    p[j]=wbv[j]*ia; q[j]=bbv[j]*ia;
  }
  float dp = dparam[d];
  int l0 = g*LC;
  #pragma unroll 2
  for (int i=0;i<LC;i++){
    int l = l0+i;
    float x  = xs[(size_t)l*Dr + d];
    float dl = softplus_fast(dp + z[l]);
    float x2 = x*x;
    float y = 0.f;
    #pragma unroll
    for (int j=0;j<4;j++){
      float Ab = exp2_hw(dl*ad2[j]);
      float Bx = (Ab-1.f)*fmaf(x2, p[j], x*q[j]);
      h[j] = fmaf(Ab, h[j], Bx);
      y = fmaf(h[j], fmaf(x, wc[j], bc[j]), y);
    }
    f32x4 hv = {h[0],h[1],h[2],h[3]};
    __builtin_nontemporal_store(hv, (f32x4*)(hs + (size_t)l*DN + d*Nr + n4*4));
    y += __shfl_xor(y, 1, 64);
    y += __shfl_xor(y, 2, 64);
    if (n4 == 0) __builtin_nontemporal_store(y, &ys[(size_t)l*Dr + d]);
  }
}

extern "C" void kernel_launch(void* const* d_in, const int* in_sizes, int n_in,
                              void* d_out, int out_size, void* d_ws, size_t ws_size,
                              hipStream_t stream) {
  const float* xs     = (const float*)d_in[0];
  const float* WB     = (const float*)d_in[1];
  const float* bB     = (const float*)d_in[2];
  const float* WC     = (const float*)d_in[3];
  const float* bC     = (const float*)d_in[4];
  const float* WD     = (const float*)d_in[5];
  const float* bD     = (const float*)d_in[6];
  const float* lnA    = (const float*)d_in[7];
  const float* dparam = (const float*)d_in[8];

  float* ys = (float*)d_out;
  float* hs = ys + (size_t)Lr*Dr;

  float* z     = (float*)d_ws;          // Lr
  float* aggA  = z + Lr;                // GDN (4 MB)
  float* aggB  = aggA + GDN;            // GDN
  float* carry = aggB + GDN;            // GDN  (total ~12.6 MB)

  k_rowdot<<<Lr, 256, 0, stream>>>(xs, WD, bD, z);
  k_phase1<<<(Gc*Dr*4)/256, 256, 0, stream>>>(xs, WB, bB, lnA, dparam, z, aggA, aggB);
  k_carry<<<DN/64, 64, 0, stream>>>(aggA, aggB, carry);
  k_phase3<<<(Gc*Dr*4)/256, 256, 0, stream>>>(xs, WB, bB, WC, bC, lnA, dparam, z, carry, ys, hs);
}

// Round 13
// 56.020 us; speedup vs baseline: 2.7917x; 1.2095x over previous
//
#include <hip/hip_runtime.h>

#define Lr 2048
#define Dr 1024
#define Nr 16
#define Gc 64           // chunks along L
#define LC (Lr/Gc)      // 32
#define DN (Dr*Nr)      // 16384
#define GDN (Gc*DN)

#define LOG2E 1.442695041f
#define LN2   0.69314718056f

typedef float f32x4 __attribute__((ext_vector_type(4)));

__device__ __forceinline__ float exp2_hw(float x){ return __builtin_amdgcn_exp2f(x); }
__device__ __forceinline__ float log2_hw(float x){ return __builtin_amdgcn_logf(x); }
__device__ __forceinline__ float exp_hw(float x) { return exp2_hw(x*LOG2E); }
__device__ __forceinline__ float softplus_fast(float x){
  float t = exp2_hw(-LOG2E*fabsf(x));
  return fmaxf(x, 0.f) + LN2*log2_hw(1.f + t);
}

// z[l] = dot(xs[l,:], WD) + bD  (separate tiny kernel; folding into phase
// kernels costs 16x redundant xs reads, +50us measured R9)
__global__ void k_rowdot(const float* __restrict__ xs, const float* __restrict__ WD,
                         const float* __restrict__ bD, float* __restrict__ z){
  int l = blockIdx.x;
  const float4* row = (const float4*)(xs + (size_t)l*Dr);
  const float4* w4  = (const float4*)WD;
  int i = threadIdx.x;           // Dr/4 == 256 == blockDim
  float4 a = row[i], b = w4[i];
  float s = fmaf(a.x,b.x, fmaf(a.y,b.y, fmaf(a.z,b.z, a.w*b.w)));
  #pragma unroll
  for (int off = 32; off > 0; off >>= 1) s += __shfl_down(s, off, 64);
  __shared__ float red[4];
  int wid = threadIdx.x >> 6, lane = threadIdx.x & 63;
  if (lane == 0) red[wid] = s;
  __syncthreads();
  if (threadIdx.x == 0) z[l] = red[0] + red[1] + red[2] + red[3] + bD[0];
}

// Phase 1 (R5-proven): thread per (g, d, n-quad); 4 chains/thread; n4-fastest
// lane map so each agg float4 store instr is wave-contiguous 1KB (whole lines
// from one wave — d-fastest variant caused cross-XCD partial-line RMW, R12).
__global__ __launch_bounds__(256) void k_phase1(
    const float* __restrict__ xs, const float* __restrict__ WB,
    const float* __restrict__ bB,
    const float* __restrict__ lnA, const float* __restrict__ dparam,
    const float* __restrict__ z,
    float* __restrict__ aggA, float* __restrict__ aggB){
  int t  = blockIdx.x*256 + threadIdx.x;
  int g  = t >> 12;             // Dr*4 = 4096 threads per chunk
  int r  = t & 4095;
  int d  = r >> 2;
  int n4 = r & 3;
  float4 la = *(const float4*)(lnA + d*Nr + n4*4);
  float4 wb = *(const float4*)(WB  + n4*4);
  float4 bb = *(const float4*)(bB  + n4*4);
  float lav[4] = {la.x,la.y,la.z,la.w};
  float wbv[4] = {wb.x,wb.y,wb.z,wb.w};
  float bbv[4] = {bb.x,bb.y,bb.z,bb.w};
  float ad2[4], p[4], q[4], Ap[4], Bc[4];
  #pragma unroll
  for (int j=0;j<4;j++){
    float a = -exp_hw(lav[j]);
    ad2[j] = a*LOG2E;
    float ia = 1.f/a;
    p[j]=wbv[j]*ia; q[j]=bbv[j]*ia; Ap[j]=1.f; Bc[j]=0.f;
  }
  float dp = dparam[d];
  int l0 = g*LC;
  #pragma unroll 2
  for (int i=0;i<LC;i++){
    int l = l0+i;
    float x  = xs[(size_t)l*Dr + d];
    float dl = softplus_fast(dp + z[l]);
    float x2 = x*x;
    #pragma unroll
    for (int j=0;j<4;j++){
      float Ab = exp2_hw(dl*ad2[j]);
      float Bx = (Ab-1.f)*fmaf(x2, p[j], x*q[j]);
      Ap[j] *= Ab;
      Bc[j] = fmaf(Ab, Bc[j], Bx);
    }
  }
  *(float4*)(aggA + (size_t)g*DN + d*Nr + n4*4) = make_float4(Ap[0],Ap[1],Ap[2],Ap[3]);
  *(float4*)(aggB + (size_t)g*DN + d*Nr + n4*4) = make_float4(Bc[0],Bc[1],Bc[2],Bc[3]);
}

// Phase 2 (R5-proven): per-chain serial scan over 64 chunks; unroll 8.
__global__ __launch_bounds__(64) void k_carry(
    const float* __restrict__ aggA, const float* __restrict__ aggB,
    float* __restrict__ carry){
  const int t = blockIdx.x*64 + threadIdx.x;   // chain id = d*Nr+n
  float h = 0.f;
  #pragma unroll 8
  for (int g=0; g<Gc; g++){
    carry[(size_t)g*DN + t] = h;
    h = fmaf(aggA[(size_t)g*DN + t], h, aggB[(size_t)g*DN + t]);
  }
}

// Phase 3: R5-exact EXCEPT plain stores instead of nontemporal (this round's
// single A/B variable: fills prove 6.6+ TB/s with plain stores; nt bypasses
// L2 write-combining).
__global__ __launch_bounds__(256) void k_phase3(
    const float* __restrict__ xs, const float* __restrict__ WB,
    const float* __restrict__ bB, const float* __restrict__ WC,
    const float* __restrict__ bC,
    const float* __restrict__ lnA, const float* __restrict__ dparam,
    const float* __restrict__ z, const float* __restrict__ carry,
    float* __restrict__ ys, float* __restrict__ hs){
  int t  = blockIdx.x*256 + threadIdx.x;
  int g  = t >> 12;
  int r  = t & 4095;
  int d  = r >> 2;
  int n4 = r & 3;
  float4 la = *(const float4*)(lnA + d*Nr + n4*4);
  float4 wb = *(const float4*)(WB  + n4*4);
  float4 bb = *(const float4*)(bB  + n4*4);
  float4 wcv= *(const float4*)(WC  + n4*4);
  float4 bcv= *(const float4*)(bC  + n4*4);
  float4 h0 = *(const float4*)(carry + (size_t)g*DN + d*Nr + n4*4);
  float lav[4] = {la.x,la.y,la.z,la.w};
  float wbv[4] = {wb.x,wb.y,wb.z,wb.w};
  float bbv[4] = {bb.x,bb.y,bb.z,bb.w};
  float wc[4]  = {wcv.x,wcv.y,wcv.z,wcv.w};
  float bc[4]  = {bcv.x,bcv.y,bcv.z,bcv.w};
  float h[4]   = {h0.x,h0.y,h0.z,h0.w};
  float ad2[4], p[4], q[4];
  #pragma unroll
  for (int j=0;j<4;j++){
    float a = -exp_hw(lav[j]);
    ad2[j] = a*LOG2E;
    float ia = 1.f/a;
    p[j]=wbv[j]*ia; q[j]=bbv[j]*ia;
  }
  float dp = dparam[d];
  int l0 = g*LC;
  #pragma unroll 2
  for (int i=0;i<LC;i++){
    int l = l0+i;
    float x  = xs[(size_t)l*Dr + d];
    float dl = softplus_fast(dp + z[l]);
    float x2 = x*x;
    float y = 0.f;
    #pragma unroll
    for (int j=0;j<4;j++){
      float Ab = exp2_hw(dl*ad2[j]);
      float Bx = (Ab-1.f)*fmaf(x2, p[j], x*q[j]);
      h[j] = fmaf(Ab, h[j], Bx);
      y = fmaf(h[j], fmaf(x, wc[j], bc[j]), y);
    }
    *(f32x4*)(hs + (size_t)l*DN + d*Nr + n4*4) = (f32x4){h[0],h[1],h[2],h[3]};
    // reduce y over the 4 n-lanes sharing this d (lanes 4k..4k+3)
    y += __shfl_xor(y, 1, 64);
    y += __shfl_xor(y, 2, 64);
    if (n4 == 0) ys[(size_t)l*Dr + d] = y;
  }
}

extern "C" void kernel_launch(void* const* d_in, const int* in_sizes, int n_in,
                              void* d_out, int out_size, void* d_ws, size_t ws_size,
                              hipStream_t stream) {
  const float* xs     = (const float*)d_in[0];
  const float* WB     = (const float*)d_in[1];
  const float* bB     = (const float*)d_in[2];
  const float* WC     = (const float*)d_in[3];
  const float* bC     = (const float*)d_in[4];
  const float* WD     = (const float*)d_in[5];
  const float* bD     = (const float*)d_in[6];
  const float* lnA    = (const float*)d_in[7];
  const float* dparam = (const float*)d_in[8];

  float* ys = (float*)d_out;
  float* hs = ys + (size_t)Lr*Dr;

  float* z     = (float*)d_ws;          // Lr
  float* aggA  = z + Lr;                // GDN (4 MB)
  float* aggB  = aggA + GDN;            // GDN
  float* carry = aggB + GDN;            // GDN  (total ~12.6 MB)

  k_rowdot<<<Lr, 256, 0, stream>>>(xs, WD, bD, z);
  k_phase1<<<(Gc*Dr*4)/256, 256, 0, stream>>>(xs, WB, bB, lnA, dparam, z, aggA, aggB);
  k_carry<<<DN/64, 64, 0, stream>>>(aggA, aggB, carry);
  k_phase3<<<(Gc*Dr*4)/256, 256, 0, stream>>>(xs, WB, bB, WC, bC, lnA, dparam, z, carry, ys, hs);
}